// Round 6
// baseline (416.987 us; speedup 1.0000x reference)
//
#include <hip/hip_runtime.h>

#define NU 100000
#define NI 100000
#define DF 128
#define CAP 32            // per-dst slot cap (Poisson(8): P(deg>32) ~ 1e-11)
#define BCAP 768          // per-bucket edge cap (mean 512, +11 sigma margin)
#define NBKT 1600         // dst >> 6 buckets (ceil(100000/64) = 1563)
#define CHUNK 4096        // edges per binning block (16/thread)

typedef __attribute__((ext_vector_type(8))) short bf16x8;
typedef __attribute__((ext_vector_type(4))) float f32x4;
typedef __attribute__((ext_vector_type(2))) float f32x2;

__device__ __forceinline__ unsigned short f2bf(float f) {
    unsigned u = __float_as_uint(f);
    return (unsigned short)((u + 0x7fffu + ((u >> 16) & 1u)) >> 16);
}
__device__ __forceinline__ float bflo(unsigned v) { return __uint_as_float(v << 16); }
__device__ __forceinline__ float bfhi(unsigned v) { return __uint_as_float(v & 0xffff0000u); }

// ---------------------------------------------------------------------------
// Weights fp32 -> bf16 ([W_f | W_rb | W_r]) + zero bcnt + zero pad rows
// (row NU of each Wh table = sentinel target for tail loads in bagg).
// ---------------------------------------------------------------------------
__global__ void wcvt_kernel(const float* __restrict__ W0,
                            const float* __restrict__ W1,
                            const float* __restrict__ W2,
                            unsigned short* __restrict__ out,
                            int* __restrict__ bcnt,
                            unsigned short* __restrict__ Wh_f,
                            unsigned short* __restrict__ Wh_rb,
                            unsigned short* __restrict__ Wh_r)
{
    const int i = blockIdx.x * 256 + threadIdx.x;
    if (i < 3 * 16384) {
        const float* src = (i < 16384) ? W0 : ((i < 32768) ? W1 : W2);
        out[i] = f2bf(src[i & 16383]);
    }
    if (i < 3 * NBKT * 16) bcnt[i] = 0;
    if (i < 3 * DF) {
        unsigned short* zp = (i < DF) ? Wh_f : ((i < 2 * DF) ? Wh_rb : Wh_r);
        zp[(size_t)NU * DF + (i & (DF - 1))] = 0;
    }
}

// ---------------------------------------------------------------------------
// bf16 MFMA GEMM. A-tile staged through LDS with fully-coalesced float4
// reads (on-the-fly bf16 convert, XOR-swizzled 32-KB tile); MFMA fragments
// from ds_read_b128; same LDS reused for coalesced output staging.
// ---------------------------------------------------------------------------
__device__ __forceinline__ void stage_a(const float* __restrict__ A,
                                        int rowbase, int M,
                                        unsigned short* __restrict__ lds, int tid)
{
#pragma unroll
    for (int it = 0; it < 16; ++it) {
        const int idx = it * 256 + tid;          // 4096 float4 chunks
        const int row = idx >> 5;                // 32 float4 per 128-float row
        const int c4  = idx & 31;
        const int rr  = min(rowbase + row, M - 1);   // tail-safe
        const float4 f = *(const float4*)(A + (size_t)rr * DF + c4 * 4);
        ushort4 h;
        h.x = f2bf(f.x); h.y = f2bf(f.y); h.z = f2bf(f.z); h.w = f2bf(f.w);
        *(ushort4*)((char*)lds + ((row * 256 + c4 * 8) ^ ((row & 7) << 4))) = h;
    }
}

__device__ __forceinline__ void frag_from_lds(const unsigned short* __restrict__ lds,
                                              int wv, int q, int n,
                                              bf16x8 afrag[2][4])
{
#pragma unroll
    for (int t = 0; t < 2; ++t) {
        const int row = wv * 32 + t * 16 + n;
#pragma unroll
        for (int s = 0; s < 4; ++s)
            afrag[t][s] = *(const bf16x8*)((const char*)lds +
                ((row * 256 + q * 16 + s * 64) ^ ((row & 7) << 4)));
    }
}

__device__ __forceinline__ void mat_pass(const bf16x8 afrag[2][4],
                                         const unsigned short* __restrict__ Wbp,
                                         const float* __restrict__ bias,
                                         unsigned short* __restrict__ ot,
                                         int wv, int q, int n)
{
#pragma unroll 2
    for (int c = 0; c < 8; ++c) {
        const unsigned short* wp = Wbp + (size_t)(c * 16 + n) * DF + q * 8;
        bf16x8 bfrag[4];
#pragma unroll
        for (int s = 0; s < 4; ++s)
            bfrag[s] = *(const bf16x8*)(wp + s * 32);

        f32x4 acc0 = {0.f, 0.f, 0.f, 0.f};
        f32x4 acc1 = {0.f, 0.f, 0.f, 0.f};
#pragma unroll
        for (int s = 0; s < 4; ++s) {
            acc0 = __builtin_amdgcn_mfma_f32_16x16x32_bf16(afrag[0][s], bfrag[s], acc0, 0, 0, 0);
            acc1 = __builtin_amdgcn_mfma_f32_16x16x32_bf16(afrag[1][s], bfrag[s], acc1, 0, 0, 0);
        }

        const float bv = bias[c * 16 + n];
        const int col2 = (c * 16 + n) * 2;
#pragma unroll
        for (int i = 0; i < 4; ++i) {
            const int r0 = wv * 32 + q * 4 + i;      // r1 = r0+16 shares (r&7)
            const int swz = (r0 & 7) << 4;
            *(unsigned short*)((char*)ot + ((r0 * 256 + col2) ^ swz))        = f2bf(acc0[i] + bv);
            *(unsigned short*)((char*)ot + (((r0 + 16) * 256 + col2) ^ swz)) = f2bf(acc1[i] + bv);
        }
    }
}

__device__ __forceinline__ void flush_tile(const unsigned short* __restrict__ ot,
                                           unsigned short* __restrict__ Wh,
                                           int rowbase, int M, int tid)
{
    __syncthreads();   // all ds_writes of this pass done
#pragma unroll
    for (int it = 0; it < 8; ++it) {
        const int chunk = it * 256 + tid;            // 2048 x 16B chunks
        const int row = chunk >> 4;
        const int lbyte = chunk * 16;
        const uint4 v = *(const uint4*)((const char*)ot + (lbyte ^ ((row & 7) << 4)));
        if (rowbase + row < M)
            *(uint4*)((char*)Wh + (size_t)(rowbase + row) * 256 + (lbyte & 255)) = v;
    }
    __syncthreads();   // safe to overwrite LDS tile
}

__global__ __launch_bounds__(256)
void gemm3_kernel(const float* __restrict__ Au, const float* __restrict__ Ai,
                  const unsigned short* __restrict__ Wb,
                  const float* __restrict__ b_f, const float* __restrict__ b_r,
                  const float* __restrict__ b_rb,
                  unsigned short* __restrict__ Wh_f,
                  unsigned short* __restrict__ Wh_r,
                  unsigned short* __restrict__ Wh_rb, int M)
{
    __shared__ unsigned short lds[128 * 128];        // 32 KB: A-tile, then ot
    const int tid  = threadIdx.x;
    const int lane = tid & 63;
    const int wv   = tid >> 6;
    const int q    = lane >> 4;
    const int n    = lane & 15;
    const int rowbase = blockIdx.x * 128;

    bf16x8 afrag[2][4];
    stage_a(Au, rowbase, M, lds, tid);
    __syncthreads();
    frag_from_lds(lds, wv, q, n, afrag);
    __syncthreads();                                 // frags in regs; reuse lds
    mat_pass(afrag, Wb,             b_f, lds, wv, q, n);
    flush_tile(lds, Wh_f, rowbase, M, tid);
    mat_pass(afrag, Wb + 2 * 16384, b_r, lds, wv, q, n);
    flush_tile(lds, Wh_r, rowbase, M, tid);

    stage_a(Ai, rowbase, M, lds, tid);
    __syncthreads();
    frag_from_lds(lds, wv, q, n, afrag);
    __syncthreads();
    mat_pass(afrag, Wb + 16384,     b_rb, lds, wv, q, n);
    flush_tile(lds, Wh_rb, rowbase, M, tid);
}

// ---------------------------------------------------------------------------
// Binning: coarse buckets (dst>>6), LDS-privatized positions (unchanged).
// ---------------------------------------------------------------------------
__global__ __launch_bounds__(256)
void bin3_kernel(const int* __restrict__ src0, const int* __restrict__ dst0, int n0, int nb0,
                 const int* __restrict__ src1, const int* __restrict__ dst1, int n1, int nb1,
                 const int* __restrict__ src2, const int* __restrict__ dst2, int n2,
                 int* __restrict__ bcnt, unsigned* __restrict__ pairs)
{
    __shared__ int hist[NBKT];
    const int tid = threadIdx.x;
    int b = blockIdx.x, e;
    const int* src; const int* dst; int n;
    if (b < nb0)            { e = 0; src = src0; dst = dst0; n = n0; }
    else if (b < nb0 + nb1) { b -= nb0; e = 1; src = src1; dst = dst1; n = n1; }
    else                    { b -= nb0 + nb1; e = 2; src = src2; dst = dst2; n = n2; }
    const int base = b * CHUNK;
    int* bc = bcnt + e * NBKT * 16;
    unsigned* pr = pairs + (size_t)e * NBKT * BCAP;

    for (int j = tid; j < NBKT; j += 256) hist[j] = 0;
    __syncthreads();

    unsigned pk[16];
    int meta[16];
#pragma unroll
    for (int k = 0; k < 16; ++k) {
        const int i = base + k * 256 + tid;
        if (i < n) {
            const unsigned d = (unsigned)dst[i];
            const unsigned s = (unsigned)src[i];
            pk[k] = (s << 6) | (d & 63u);
            const int p = atomicAdd(&hist[d >> 6], 1);
            meta[k] = (int)((d >> 6) << 16) | p;
        } else meta[k] = -1;
    }
    __syncthreads();
    for (int j = tid; j < NBKT; j += 256) {
        const int c = hist[j];
        hist[j] = (c > 0) ? atomicAdd(&bc[j * 16], c) : 0;
    }
    __syncthreads();
#pragma unroll
    for (int k = 0; k < 16; ++k) {
        if (meta[k] >= 0) {
            const int bkt = meta[k] >> 16;
            const int p = hist[bkt] + (meta[k] & 0xffff);
            if (p < BCAP) pr[(size_t)bkt * BCAP + p] = pk[k];
        }
    }
}

// ---------------------------------------------------------------------------
// Wave-per-node gather, branch-free edition:
//  - slot lists hold PRE-SCALED byte offsets (src*256), sentinel-initialized
//    to the zeroed pad row (NU*256) -> no tail predication, no masking.
//  - loads use SGPR base + 32-bit VGPR offset (slot + lane*4): one v_add of
//    address VALU per edge.
//  - slot broadcast via uniform-address ds_read_b128: 4 slots per LDS op.
//  - output stored nontemporally (write-once, never re-read) to reduce L3
//    pollution so Wh tables stay cache-resident.
// ---------------------------------------------------------------------------
__global__ __launch_bounds__(256, 8)
void bagg_kernel(const unsigned short* __restrict__ Wh_f,
                 const unsigned short* __restrict__ Wh_rb,
                 const unsigned short* __restrict__ Wh_r,
                 const int* __restrict__ bcnt, const unsigned* __restrict__ pairs,
                 float* __restrict__ out_user, float* __restrict__ out_item,
                 int nbu)
{
    __shared__ int cntA[64], cntB[64];
    __shared__ unsigned slotA[64 * CAP], slotB[64 * CAP];
    const int tid = threadIdx.x;
    const bool user = (blockIdx.x < nbu);        // user-first ordering
    const int bkt = user ? blockIdx.x : blockIdx.x - nbu;

    if (tid < 64) { cntA[tid] = 0; cntB[tid] = 0; }
    {   // sentinel-fill both slot arrays (pad row NU, prescaled bytes)
        const unsigned sent = (unsigned)NU * 256u;
        const uint4 s4 = {sent, sent, sent, sent};
        ((uint4*)slotA)[tid] = s4; ((uint4*)slotA)[tid + 256] = s4;
        ((uint4*)slotB)[tid] = s4; ((uint4*)slotB)[tid + 256] = s4;
    }
    __syncthreads();

    const int wv = tid >> 6, lane = tid & 63;
    const unsigned lane4 = (unsigned)lane * 4u;

    if (user) {
        const int nf  = min(bcnt[0 * NBKT * 16 + bkt * 16], BCAP);
        const int nrb = min(bcnt[1 * NBKT * 16 + bkt * 16], BCAP);
        const unsigned* prf  = pairs + (size_t)bkt * BCAP;
        const unsigned* prrb = pairs + (size_t)NBKT * BCAP + (size_t)bkt * BCAP;
        for (int i = tid; i < nf; i += 256) {
            const unsigned v = prf[i];
            const int dl = v & 63;
            const int p = atomicAdd(&cntA[dl], 1);
            if (p < CAP) slotA[dl * CAP + p] = (v & ~63u) << 2;   // src*256
        }
        for (int i = tid; i < nrb; i += 256) {
            const unsigned v = prrb[i];
            const int dl = v & 63;
            const int p = atomicAdd(&cntB[dl], 1);
            if (p < CAP) slotB[dl * CAP + p] = (v & ~63u) << 2;
        }
        __syncthreads();

        const char* basef  = (const char*)Wh_f;
        const char* baserb = (const char*)Wh_rb;
        for (int t = 0; t < 16; ++t) {
            const int dl = wv * 16 + t;
            const int node = bkt * 64 + dl;
            if (node >= NU) break;                    // wave-uniform
            const int degf  = cntA[dl];
            const int degrb = cntB[dl];
            const int dmax  = (max(min(degf, CAP), min(degrb, CAP)) + 3) & ~3;
            const unsigned* slf = &slotA[dl * CAP];
            const unsigned* slb = &slotB[dl * CAP];

            f32x2 af = {0.f, 0.f}, ab = {0.f, 0.f};
            for (int j = 0; j < dmax; j += 4) {
                const uint4 sf4 = *(const uint4*)(slf + j);   // broadcast
                const uint4 sb4 = *(const uint4*)(slb + j);
                unsigned uf[4], ub[4];
                uf[0] = *(const unsigned*)(basef  + (sf4.x + lane4));
                ub[0] = *(const unsigned*)(baserb + (sb4.x + lane4));
                uf[1] = *(const unsigned*)(basef  + (sf4.y + lane4));
                ub[1] = *(const unsigned*)(baserb + (sb4.y + lane4));
                uf[2] = *(const unsigned*)(basef  + (sf4.z + lane4));
                ub[2] = *(const unsigned*)(baserb + (sb4.z + lane4));
                uf[3] = *(const unsigned*)(basef  + (sf4.w + lane4));
                ub[3] = *(const unsigned*)(baserb + (sb4.w + lane4));
#pragma unroll
                for (int k = 0; k < 4; ++k) {
                    af += (f32x2){bflo(uf[k]), bfhi(uf[k])};
                    ab += (f32x2){bflo(ub[k]), bfhi(ub[k])};
                }
            }
            const float invf  = degf  > 0 ? 1.f / (float)degf  : 0.f;
            const float invrb = degrb > 0 ? 1.f / (float)degrb : 0.f;
            const f32x2 r = af * (f32x2){invf, invf} + ab * (f32x2){invrb, invrb};
            __builtin_nontemporal_store(r,
                (f32x2*)(out_user + (size_t)node * DF + lane * 2));
        }
    } else {
        const int nr = min(bcnt[2 * NBKT * 16 + bkt * 16], BCAP);
        const unsigned* prr = pairs + 2 * (size_t)NBKT * BCAP + (size_t)bkt * BCAP;
        for (int i = tid; i < nr; i += 256) {
            const unsigned v = prr[i];
            const int dl = v & 63;
            const int p = atomicAdd(&cntA[dl], 1);
            if (p < CAP) slotA[dl * CAP + p] = (v & ~63u) << 2;
        }
        __syncthreads();

        const char* baser = (const char*)Wh_r;
        for (int t = 0; t < 16; ++t) {
            const int dl = wv * 16 + t;
            const int node = bkt * 64 + dl;
            if (node >= NI) break;                    // wave-uniform
            const int degr = cntA[dl];
            const int drp  = (min(degr, CAP) + 7) & ~7;
            const unsigned* slr = &slotA[dl * CAP];

            f32x2 ar = {0.f, 0.f};
            for (int j = 0; j < drp; j += 8) {
                const uint4 s0 = *(const uint4*)(slr + j);
                const uint4 s1 = *(const uint4*)(slr + j + 4);
                unsigned ur[8];
                ur[0] = *(const unsigned*)(baser + (s0.x + lane4));
                ur[1] = *(const unsigned*)(baser + (s0.y + lane4));
                ur[2] = *(const unsigned*)(baser + (s0.z + lane4));
                ur[3] = *(const unsigned*)(baser + (s0.w + lane4));
                ur[4] = *(const unsigned*)(baser + (s1.x + lane4));
                ur[5] = *(const unsigned*)(baser + (s1.y + lane4));
                ur[6] = *(const unsigned*)(baser + (s1.z + lane4));
                ur[7] = *(const unsigned*)(baser + (s1.w + lane4));
#pragma unroll
                for (int k = 0; k < 8; ++k)
                    ar += (f32x2){bflo(ur[k]), bfhi(ur[k])};
            }
            const float invr = degr > 0 ? 1.f / (float)degr : 0.f;
            const f32x2 r = ar * (f32x2){invr, invr};
            __builtin_nontemporal_store(r,
                (f32x2*)(out_item + (size_t)node * DF + lane * 2));
        }
    }
}

// ---------------------------------------------------------------------------
extern "C" void kernel_launch(void* const* d_in, const int* in_sizes, int n_in,
                              void* d_out, int out_size, void* d_ws,
                              size_t ws_size, hipStream_t stream)
{
    const float* feat_user = (const float*)d_in[0];
    const float* feat_item = (const float*)d_in[1];
    const float* W_f  = (const float*)d_in[2];
    const float* b_f  = (const float*)d_in[3];
    const float* W_r  = (const float*)d_in[4];
    const float* b_r  = (const float*)d_in[5];
    const float* W_rb = (const float*)d_in[6];
    const float* b_rb = (const float*)d_in[7];
    const int* src_f  = (const int*)d_in[8];
    const int* dst_f  = (const int*)d_in[9];
    const int* src_r  = (const int*)d_in[10];
    const int* dst_r  = (const int*)d_in[11];
    const int* src_rb = (const int*)d_in[12];
    const int* dst_rb = (const int*)d_in[13];
    const int Ef  = in_sizes[8];
    const int Er  = in_sizes[10];
    const int Erb = in_sizes[12];

    float* out_user = (float*)d_out;
    float* out_item = (float*)d_out + (size_t)NU * DF;

    char* p = (char*)d_ws;
    const size_t whsz = ((size_t)NU + 1) * DF * 2;   // +1 zero pad row
    unsigned short* Wh_f  = (unsigned short*)p;  p += whsz;                   // 25.6 MB
    unsigned short* Wh_rb = (unsigned short*)p;  p += whsz;                   // 25.6 MB
    unsigned short* Wh_r  = (unsigned short*)p;  p += whsz;                   // 25.6 MB
    unsigned* pairs = (unsigned*)p;  p += 3 * (size_t)NBKT * BCAP * 4;        // 14.75 MB
    int* bcnt = (int*)p;             p += 3 * (size_t)NBKT * 16 * 4;          // 307 KB
    unsigned short* Wb = (unsigned short*)p;                                  // 96 KB

    wcvt_kernel<<<300, 256, 0, stream>>>(W_f, W_rb, W_r, Wb, bcnt,
                                         Wh_f, Wh_rb, Wh_r);

    gemm3_kernel<<<(NU + 127) / 128, 256, 0, stream>>>(
        feat_user, feat_item, Wb, b_f, b_r, b_rb, Wh_f, Wh_r, Wh_rb, NU);

    const int nb_f  = (Ef  + CHUNK - 1) / CHUNK;
    const int nb_rb = (Erb + CHUNK - 1) / CHUNK;
    const int nb_r  = (Er  + CHUNK - 1) / CHUNK;
    bin3_kernel<<<nb_f + nb_rb + nb_r, 256, 0, stream>>>(
        src_f,  dst_f,  Ef,  nb_f,
        src_rb, dst_rb, Erb, nb_rb,
        src_r,  dst_r,  Er,  bcnt, pairs);

    const int nbu = (NU + 63) / 64;   // 1563
    const int nbi = (NI + 63) / 64;   // 1563
    bagg_kernel<<<nbu + nbi, 256, 0, stream>>>(
        Wh_f, Wh_rb, Wh_r, bcnt, pairs, out_user, out_item, nbu);
}